// Round 17
// baseline (67.847 us; speedup 1.0000x reference)
//
#include <hip/hip_runtime.h>
#include <hip/hip_bf16.h>
#include <math.h>

#define BS 8192
#define D 128
#define NROWS 16384               // 2*BS
#define NSPLIT 16                 // col splits
#define COLS_PER_BLOCK 1024
#define NCHUNK (COLS_PER_BLOCK / 16)      // 64 chunks of 16 cols
#define NPART NSPLIT                      // 16 partial planes
#define NBLK (NSPLIT * (BS / 128))        // 16 x 64 = 1024 blocks

typedef int i32x8 __attribute__((ext_vector_type(8)));
typedef float f32x4 __attribute__((ext_vector_type(4)));

#define LN2F 0.6931471805599453f
// store scale: elements written as x * 2^4 * sqrt(log2e) / ||row||; HW E8M0
// scale 2^-4 on A and B restores acc = sim * log2e exactly (powers of 2).
#define STORE_SCALE 19.217958569050494f   // 16 * 1.2011224087864498
#define E8M0_M4 123                       // 2^(123-127) = 2^-4

#if __has_builtin(__builtin_amdgcn_exp2f)
#define EXP2F(x) __builtin_amdgcn_exp2f(x)
#else
#define EXP2F(x) exp2f(x)
#endif

// Layout of catF (fp8, "16-row-group tiled"): byte addr of (row, k) =
//   (row>>4)*2048 + (k>>5)*512 + (row&15)*32 + (k&31)
// -> a 16-row x K=128 group is one contiguous 2 KiB cell; an MFMA fragment
//    (lanes: l15=row/col, l4=k-block-of-32) is lane 32B at l4*512+l15*32.

// Kernel 1: row norms + scaled fp8(e4m3) conversion into catF.
// Also re-zeroes the completion counter every call (graph-replay safe).
__global__ __launch_bounds__(256) void nrm_cvt(const float* __restrict__ f,
                                               const float* __restrict__ noise,
                                               char* __restrict__ catF,
                                               unsigned int* __restrict__ cnt) {
  if (blockIdx.x == 0 && threadIdx.x == 0) cnt[0] = 0;
  const int lane = threadIdx.x & 63;
  const int wv = threadIdx.x >> 6;
  const int row = blockIdx.x * 4 + wv;
  const float* src = (row < BS) ? (noise + (size_t)row * D) : (f + (size_t)(row - BS) * D);
  float2 v = ((const float2*)src)[lane];   // k = 2*lane, 2*lane+1 (same 32-cell)
  float ss = v.x * v.x + v.y * v.y;
#pragma unroll
  for (int m = 1; m <= 32; m <<= 1) ss += __shfl_xor(ss, m, 64);
  const float s = STORE_SCALE / sqrtf(ss);
  const int packed = __builtin_amdgcn_cvt_pk_fp8_f32(v.x * s, v.y * s, 0, false);
  char* dst = catF + ((size_t)(row >> 4) << 11) + ((lane >> 4) << 9) +
              ((row & 15) << 5) + ((lane & 15) << 1);
  *(unsigned short*)dst = (unsigned short)(packed & 0xffff);
}

// Kernel 2: fused GEMM + exp2 + row-sum + LAST-BLOCK FINALIZE, MX-FP8 K=128.
// 32-row waves (R16), 64 chunks each, processed in PAIRS: 8 MFMAs issue
// before either chunk's exp epilogue -> one chunk's trans/VALU overlaps the
// sibling's MFMA latency within the wave (the only overlap available at low
// effective waves/SIMD). After the plane store, each block bumps a counter
// (threadfence + device atomic); the last arriver sums the 16 partial planes
// + pos and writes the scalar loss — deterministic (plain stores, fixed-order
// sums; only the winner's identity varies). Kills 2 dispatches.
__global__ __launch_bounds__(256) void infonce_main(
    const char* __restrict__ catF,
    float* __restrict__ ws_neg, float* __restrict__ ws_pos,
    unsigned int* __restrict__ cnt, float* __restrict__ out) {
  __shared__ int flag;
  __shared__ float red[4];
  const int tid = threadIdx.x;
  const int lane = tid & 63;
  const int w = tid >> 6;
  const int l15 = lane & 15, l4 = lane >> 4;
  const int nb = blockIdx.x, mb = blockIdx.y;
  const int growbase = mb * 128 + w * 32;    // 32 rows per wave
  const int col0 = nb * COLS_PER_BLOCK;
  const int lbase = l4 * 512 + l15 * 32;

  // A fragments: 32 f-rows x K=128 fp8 (16 VGPRs)
  i32x8 a[2];
  {
    const char* ab = catF + ((size_t)((BS + growbase) >> 4) << 11) + lbase;
    a[0] = *(const i32x8*)(ab);
    a[1] = *(const i32x8*)(ab + 2048);
  }

  f32x4 rs[2];
  const f32x4 z = {0.f, 0.f, 0.f, 0.f};
  rs[0] = z;
  rs[1] = z;

  const char* bl = catF + ((size_t)(col0 >> 4) << 11) + lbase;

  // 4-slot ring: pair p uses slots (0,1) or (2,3); prefetch 4 chunks ahead
  i32x8 bb[4];
  bb[0] = *(const i32x8*)(bl);
  bb[1] = *(const i32x8*)(bl + 2048);
  bb[2] = *(const i32x8*)(bl + 4096);
  bb[3] = *(const i32x8*)(bl + 6144);

  auto epi = [&](const f32x4* acc, int c0) {
    const bool dPos = (c0 >= growbase) && (c0 < growbase + 32);
    const bool dSelf = (c0 - BS >= growbase) && (c0 - BS < growbase + 32);
    if (!dPos && !dSelf) {
#pragma unroll
      for (int rf = 0; rf < 2; rf++) {
        f32x4 e;
#pragma unroll
        for (int r = 0; r < 4; r++) e[r] = EXP2F(acc[rf][r]);
        rs[rf] += e;
      }
    } else {
#pragma unroll
      for (int rf = 0; rf < 2; rf++)
#pragma unroll
        for (int r = 0; r < 4; r++) {
          const int grow = growbase + rf * 16 + l4 * 4 + r;
          const int gcol = c0 + l15;
          const float v = acc[rf][r];
          const bool ex = dPos ? (gcol == grow) : (gcol == grow + BS);
          if (dPos && gcol == grow) ws_pos[grow] = v;  // sim_pos * log2e
          rs[rf][r] += ex ? 0.f : EXP2F(v);
        }
    }
  };

#pragma unroll
  for (int ph = 0; ph < NCHUNK / 2; ++ph) {
    const int c = 2 * ph;
    const int s0 = c & 3;          // 0,2,0,2,...
    const int s1 = s0 + 1;

    // 8 MFMAs for the pair issued before either epilogue
    f32x4 accA[2], accB[2];
#pragma unroll
    for (int rf = 0; rf < 2; rf++)
      accA[rf] = __builtin_amdgcn_mfma_scale_f32_16x16x128_f8f6f4(
          a[rf], bb[s0], z, 0, 0, 0, E8M0_M4, 0, E8M0_M4);
#pragma unroll
    for (int rf = 0; rf < 2; rf++)
      accB[rf] = __builtin_amdgcn_mfma_scale_f32_16x16x128_f8f6f4(
          a[rf], bb[s1], z, 0, 0, 0, E8M0_M4, 0, E8M0_M4);

    // prefetch 4 chunks ahead into the just-consumed slots
    if (c + 4 < NCHUNK) bb[s0] = *(const i32x8*)(bl + (size_t)(c + 4) * 2048);
    if (c + 5 < NCHUNK) bb[s1] = *(const i32x8*)(bl + (size_t)(c + 5) * 2048);

    epi(accA, col0 + c * 16);
    epi(accB, col0 + c * 16 + 16);
  }

  // reduce rowsums across the 16 lanes (l15) sharing each row
  float rowsum[8];
#pragma unroll
  for (int rf = 0; rf < 2; rf++)
#pragma unroll
    for (int r = 0; r < 4; r++) {
      float v = rs[rf][r];
      v += __shfl_xor(v, 1, 64);
      v += __shfl_xor(v, 2, 64);
      v += __shfl_xor(v, 4, 64);
      v += __shfl_xor(v, 8, 64);
      rowsum[rf * 4 + r] = v;
    }
  if (l15 == 0) {
    float* dst = ws_neg + (size_t)nb * BS + growbase;
#pragma unroll
    for (int rf = 0; rf < 2; rf++)
#pragma unroll
      for (int r = 0; r < 4; r++) dst[rf * 16 + l4 * 4 + r] = rowsum[rf * 4 + r];
  }

  // ---- last-block finalize (block-uniform branch) ----
  __syncthreads();
  if (tid == 0) {
    __threadfence();  // release: planes + pos visible before the bump
    flag = (atomicAdd(cnt, 1u) == (unsigned)(NBLK - 1));
  }
  __syncthreads();
  if (!flag) return;
  __threadfence();    // acquire: see all blocks' stores

  float local = 0.f;
  for (int row = tid; row < BS; row += 256) {
    float neg = 0.f;
#pragma unroll
    for (int p = 0; p < NPART; p++) neg += ws_neg[(size_t)p * BS + row];
    // loss = log(neg_sum + eps) - sim_pos ; sim_pos = (sim*log2e)*ln2
    local += logf(neg + 1e-6f) - ws_pos[row] * LN2F;
  }
#pragma unroll
  for (int m = 1; m <= 32; m <<= 1) local += __shfl_xor(local, m, 64);
  if (lane == 0) red[w] = local;
  __syncthreads();
  if (tid == 0) out[0] = (red[0] + red[1] + red[2] + red[3]) * (1.f / BS);
}

extern "C" void kernel_launch(void* const* d_in, const int* in_sizes, int n_in,
                              void* d_out, int out_size, void* d_ws, size_t ws_size,
                              hipStream_t stream) {
  const float* f = (const float*)d_in[0];
  const float* noise = (const float*)d_in[1];
  char* ws = (char*)d_ws;
  char* catF = ws;                                       // 2 MiB (fp8 tiled)
  float* ws_pos = (float*)(ws + (size_t)NROWS * D);      // 32 KiB
  float* ws_neg = ws_pos + BS;                           // 512 KiB
  unsigned int* cnt = (unsigned int*)(ws_neg + (size_t)NPART * BS);

  nrm_cvt<<<NROWS / 4, 256, 0, stream>>>(f, noise, catF, cnt);
  dim3 grid(NSPLIT, BS / 128);                           // 16 x 64 = 1024 blocks
  infonce_main<<<grid, 256, 0, stream>>>(catF, ws_neg, ws_pos, cnt, (float*)d_out);
}

// Round 18
// 41.117 us; speedup vs baseline: 1.6501x; 1.6501x over previous
//
#include <hip/hip_runtime.h>
#include <hip/hip_bf16.h>
#include <math.h>

#define BS 8192
#define D 128
#define NROWS 16384               // 2*BS
#define COLS_PER_BLOCK 512
#define NCHUNK (COLS_PER_BLOCK / 16)      // 32 col-chunks of 16
#define NSPLIT (NROWS / COLS_PER_BLOCK)   // 32 col-splits
#define NPART NSPLIT                      // 32 partial buffers

typedef int i32x8 __attribute__((ext_vector_type(8)));
typedef float f32x4 __attribute__((ext_vector_type(4)));

#define LN2F 0.6931471805599453f
// store scale: elements written as x * 2^4 * sqrt(log2e) / ||row||; HW E8M0
// scale 2^-4 on A and B restores acc = sim * log2e exactly (powers of 2).
#define STORE_SCALE 19.217958569050494f   // 16 * 1.2011224087864498
#define E8M0_M4 123                       // 2^(123-127) = 2^-4

#if __has_builtin(__builtin_amdgcn_exp2f)
#define EXP2F(x) __builtin_amdgcn_exp2f(x)
#else
#define EXP2F(x) exp2f(x)
#endif

// Layout of catF (fp8, "16-row-group tiled"): byte addr of (row, k) =
//   (row>>4)*2048 + (k>>5)*512 + (row&15)*32 + (k&31)
// -> a 16-row x K=128 group is one contiguous 2 KiB cell; an MFMA fragment
//    (lanes: l15=row/col, l4=k-block-of-32) is lane 32B at l4*512+l15*32 —
//    the wave's 64x32B = the whole 2 KiB cell, fully coalesced.

// Kernel 1: row norms + scaled fp8(e4m3) conversion into catF.
// Also re-zeroes the finalize completion counter (graph-replay safe).
__global__ __launch_bounds__(256) void nrm_cvt(const float* __restrict__ f,
                                               const float* __restrict__ noise,
                                               char* __restrict__ catF,
                                               unsigned int* __restrict__ cnt) {
  if (blockIdx.x == 0 && threadIdx.x == 0) cnt[0] = 0;
  const int lane = threadIdx.x & 63;
  const int wv = threadIdx.x >> 6;
  const int row = blockIdx.x * 4 + wv;
  const float* src = (row < BS) ? (noise + (size_t)row * D) : (f + (size_t)(row - BS) * D);
  float2 v = ((const float2*)src)[lane];   // k = 2*lane, 2*lane+1 (same 32-cell)
  float ss = v.x * v.x + v.y * v.y;
#pragma unroll
  for (int m = 1; m <= 32; m <<= 1) ss += __shfl_xor(ss, m, 64);
  const float s = STORE_SCALE / sqrtf(ss);
  // pack 2 floats -> 2 OCP e4m3 bytes (low 16 bits)
  const int packed = __builtin_amdgcn_cvt_pk_fp8_f32(v.x * s, v.y * s, 0, false);
  char* dst = catF + ((size_t)(row >> 4) << 11) + ((lane >> 4) << 9) +
              ((row & 15) << 5) + ((lane & 15) << 1);
  *(unsigned short*)dst = (unsigned short)(packed & 0xffff);
}

// Kernel 2 (R13 verbatim — best measured, 40.6 us total): fused GEMM + exp2 +
// row-sum, MX-FP8 K=128, ONE mfma_scale_f32_16x16x128 per 16x16 tile.
// 4-wave blocks sharing one B slice (L1 dedup), no LDS, no barriers,
// register double-buffered B. Grid 32x32, 16 waves/CU.
__global__ __launch_bounds__(256) void infonce_main(
    const char* __restrict__ catF,
    float* __restrict__ ws_neg, float* __restrict__ ws_pos) {
  const int tid = threadIdx.x;
  const int lane = tid & 63;
  const int w = tid >> 6;
  const int l15 = lane & 15, l4 = lane >> 4;
  const int nb = blockIdx.x, mb = blockIdx.y;
  const int growbase = mb * 256 + w * 64;
  const int col0 = nb * COLS_PER_BLOCK;
  const int lbase = l4 * 512 + l15 * 32;

  // A fragments: 64 f-rows x K=128 fp8 (32 VGPRs total)
  i32x8 a[4];
  {
    const char* ab = catF + ((size_t)((BS + growbase) >> 4) << 11) + lbase;
#pragma unroll
    for (int rf = 0; rf < 4; rf++) a[rf] = *(const i32x8*)(ab + rf * 2048);
  }

  f32x4 rs[4];
  const f32x4 z = {0.f, 0.f, 0.f, 0.f};
#pragma unroll
  for (int rf = 0; rf < 4; rf++) rs[rf] = z;

  const char* bl = catF + ((size_t)(col0 >> 4) << 11) + lbase;
  i32x8 bb[2];
  bb[0] = *(const i32x8*)(bl);

#pragma unroll
  for (int ch = 0; ch < NCHUNK; ++ch) {
    const int cu = ch & 1;  // compile-time under full unroll
    if (ch + 1 < NCHUNK) bb[cu ^ 1] = *(const i32x8*)(bl + (size_t)(ch + 1) * 2048);

    f32x4 acc[4];
#pragma unroll
    for (int rf = 0; rf < 4; rf++)
      acc[rf] = __builtin_amdgcn_mfma_scale_f32_16x16x128_f8f6f4(
          a[rf], bb[cu], z, 0 /*A=fp8*/, 0 /*B=fp8*/,
          0, E8M0_M4, 0, E8M0_M4);

    // epilogue: acc = sim*log2e -> exp2, accumulate row sums, excise diagonals.
    const int c0 = col0 + ch * 16;
    const bool dPos = ((c0 & ~63) == growbase);          // cols == f-row ids
    const bool dSelf = (((c0 - BS) & ~63) == growbase);  // cols == i+bs
    if (!dPos && !dSelf) {
#pragma unroll
      for (int rf = 0; rf < 4; rf++) {
        f32x4 e;
#pragma unroll
        for (int r = 0; r < 4; r++) e[r] = EXP2F(acc[rf][r]);
        rs[rf] += e;  // f32x4 add -> v_pk_add_f32 pair
      }
    } else {
#pragma unroll
      for (int rf = 0; rf < 4; rf++)
#pragma unroll
        for (int r = 0; r < 4; r++) {
          const int grow = growbase + rf * 16 + l4 * 4 + r;
          const int gcol = c0 + l15;
          const float v = acc[rf][r];
          const bool ex = dPos ? (gcol == grow) : (gcol == grow + BS);
          if (dPos && gcol == grow) ws_pos[grow] = v;  // sim_pos * log2e
          rs[rf][r] += ex ? 0.f : EXP2F(v);
        }
    }
  }

  // reduce rowsums across the 16 lanes (l15) sharing each row
  float rowsum[16];
#pragma unroll
  for (int rf = 0; rf < 4; rf++)
#pragma unroll
    for (int r = 0; r < 4; r++) {
      float v = rs[rf][r];
      v += __shfl_xor(v, 1, 64);
      v += __shfl_xor(v, 2, 64);
      v += __shfl_xor(v, 4, 64);
      v += __shfl_xor(v, 8, 64);
      rowsum[rf * 4 + r] = v;
    }
  if (l15 == 0) {
    float* dst = ws_neg + (size_t)nb * BS + growbase;
#pragma unroll
    for (int rf = 0; rf < 4; rf++)
#pragma unroll
      for (int r = 0; r < 4; r++) dst[rf * 16 + l4 * 4 + r] = rowsum[rf * 4 + r];
  }
}

// Kernel 3: per-row loss + mean, single kernel. 32 blocks; each writes its
// block partial, bumps a device counter (release fence first); the last
// arriver reduces the 32 partials and writes the scalar. Deterministic:
// plain stores + fixed-order sums; only the winner's identity varies.
__global__ __launch_bounds__(256) void finalize(const float* __restrict__ ws_neg,
                                                const float* __restrict__ ws_pos,
                                                float* __restrict__ partial,
                                                unsigned int* __restrict__ cnt,
                                                float* __restrict__ out) {
  __shared__ float red[4];
  __shared__ int flag;
  const int tid = threadIdx.x;
  const int lane = tid & 63;
  const int w = tid >> 6;
  const int row = blockIdx.x * 256 + tid;
  float neg = 0.f;
#pragma unroll
  for (int p = 0; p < NPART; p++) neg += ws_neg[(size_t)p * BS + row];
  // loss = log(neg_sum + eps) - sim_pos ; sim_pos = (sim*log2e)*ln2
  float local = logf(neg + 1e-6f) - ws_pos[row] * LN2F;
#pragma unroll
  for (int m = 1; m <= 32; m <<= 1) local += __shfl_xor(local, m, 64);
  if (lane == 0) red[w] = local;
  __syncthreads();
  if (tid == 0) {
    partial[blockIdx.x] = red[0] + red[1] + red[2] + red[3];
    __threadfence();  // release: partial visible before the bump
    flag = (atomicAdd(cnt, 1u) == (unsigned)(BS / 256 - 1));
  }
  __syncthreads();
  if (!flag) return;
  __threadfence();    // acquire: see all blocks' partials
  if (tid < 64) {
    float v = (tid < 32) ? partial[tid] : 0.f;
#pragma unroll
    for (int m = 1; m <= 32; m <<= 1) v += __shfl_xor(v, m, 64);
    if (tid == 0) out[0] = v * (1.f / BS);
  }
}

extern "C" void kernel_launch(void* const* d_in, const int* in_sizes, int n_in,
                              void* d_out, int out_size, void* d_ws, size_t ws_size,
                              hipStream_t stream) {
  const float* f = (const float*)d_in[0];
  const float* noise = (const float*)d_in[1];
  char* ws = (char*)d_ws;
  char* catF = ws;                                       // 2 MiB (fp8 tiled)
  float* ws_pos = (float*)(ws + (size_t)NROWS * D);      // 32 KiB
  float* ws_neg = ws_pos + BS;                           // 1 MiB
  float* partial = ws_neg + (size_t)NPART * BS;          // 128 B
  unsigned int* cnt = (unsigned int*)(partial + 32);

  nrm_cvt<<<NROWS / 4, 256, 0, stream>>>(f, noise, catF, cnt);
  dim3 grid(NSPLIT, BS / 256);                           // 32 x 32 = 1024 blocks
  infonce_main<<<grid, 256, 0, stream>>>(catF, ws_neg, ws_pos);
  finalize<<<BS / 256, 256, 0, stream>>>(ws_neg, ws_pos, partial, cnt, (float*)d_out);
}